// Round 1
// baseline (1659.404 us; speedup 1.0000x reference)
//
#include <hip/hip_runtime.h>

// MHConvAttention: B=16, C=256, H=W=64, NH=8, hd=32, WS=5
// Workspace layout (bytes), total 137,101,312 required:
//   [0)            x / result  bf16  (16,256,4096)   33,554,432
//   [33554432)     qkv         bf16  (16,768,4096)  100,663,296
//   [134217728)    cl          f32   (128,32,32)        524,288
//   [134742016)    cpe_w repacked f32 (9,256,256)     2,359,296

typedef unsigned short u16;
#define HW 4096

__device__ __forceinline__ float bf2f(u16 u){
  unsigned v = ((unsigned)u) << 16;
  return __builtin_bit_cast(float, v);
}
__device__ __forceinline__ u16 f2bf(float f){
  unsigned u = __builtin_bit_cast(unsigned, f);
  u = u + 0x7fffu + ((u >> 16) & 1u);   // RNE
  return (u16)(u >> 16);
}
__device__ __forceinline__ unsigned pack2(float a, float b){
  return (unsigned)f2bf(a) | ((unsigned)f2bf(b) << 16);
}
__device__ __forceinline__ void unpack2(unsigned u, float& a, float& b){
  a = bf2f((u16)(u & 0xffffu)); b = bf2f((u16)(u >> 16));
}

// ---------------- repack cpe_w (o,c,3,3) -> (kk,o,c) ----------------
__global__ void repack_cpe(const float* __restrict__ w, float* __restrict__ out){
  int idx = blockIdx.x*256 + threadIdx.x;
  if (idx >= 9*256*256) return;
  int kk = idx >> 16;
  int o  = (idx >> 8) & 255;
  int c  = idx & 255;
  out[idx] = w[((o*256 + c)*9) + kk];
}

// ---------------- shared 8x8 FMA core ----------------
__device__ __forceinline__ void fma8x8(const float* __restrict__ Xt,
                                       const float* __restrict__ Wt,
                                       int tn, int tm, float acc[8][8]){
  #pragma unroll
  for (int k = 0; k < 16; ++k) {
    float a[8], w[8];
    *(float4*)&a[0] = *(const float4*)&Xt[k*128 + tn];
    *(float4*)&a[4] = *(const float4*)&Xt[k*128 + tn + 4];
    *(float4*)&w[0] = *(const float4*)&Wt[k*128 + tm];
    *(float4*)&w[4] = *(const float4*)&Wt[k*128 + tm + 4];
    #pragma unroll
    for (int mi = 0; mi < 8; ++mi)
      #pragma unroll
      for (int ni = 0; ni < 8; ++ni)
        acc[mi][ni] = fmaf(w[mi], a[ni], acc[mi][ni]);
  }
}

// ---------------- CPE 3x3 conv as 9 shifted GEMMs + bias + residual -> x(bf16)
__global__ __launch_bounds__(256) void conv_cpe(const float* __restrict__ src,
    const float* __restrict__ wr, const float* __restrict__ bias,
    u16* __restrict__ xout){
  __shared__ float Wt[16*128];
  __shared__ float Xt[16*128];
  const int t = threadIdx.x;
  const int hw0 = blockIdx.x * 128;
  const int y0  = hw0 >> 6;
  const int o0  = blockIdx.y * 128;
  const int b   = blockIdx.z;
  const size_t srcb = (size_t)b * 256 * HW;
  float acc[8][8] = {};
  const int wo = t >> 1, wk = (t & 1) * 8;
  const int tn = (t & 15) * 8, tm = (t >> 4) * 8;

  for (int kk = 0; kk < 9; ++kk) {
    const int dy = kk/3 - 1, dx = kk%3 - 1;
    const float* wkk = wr + kk * 65536;
    for (int c0 = 0; c0 < 256; c0 += 16) {
      float4 wv0 = *(const float4*)&wkk[(o0+wo)*256 + c0 + wk];
      float4 wv1 = *(const float4*)&wkk[(o0+wo)*256 + c0 + wk + 4];
      float av[8];
      #pragma unroll
      for (int jj = 0; jj < 8; ++jj) {
        int idx = t + 256*jj;
        int kl = idx >> 7, n = idx & 127;
        int y = y0 + (n >> 6) + dy, x = (n & 63) + dx;
        float v = 0.f;
        if ((unsigned)y < 64u && (unsigned)x < 64u)
          v = src[srcb + (size_t)(c0+kl)*HW + y*64 + x];
        av[jj] = v;
      }
      __syncthreads();
      Wt[(wk+0)*128 + wo] = wv0.x; Wt[(wk+1)*128 + wo] = wv0.y;
      Wt[(wk+2)*128 + wo] = wv0.z; Wt[(wk+3)*128 + wo] = wv0.w;
      Wt[(wk+4)*128 + wo] = wv1.x; Wt[(wk+5)*128 + wo] = wv1.y;
      Wt[(wk+6)*128 + wo] = wv1.z; Wt[(wk+7)*128 + wo] = wv1.w;
      #pragma unroll
      for (int jj = 0; jj < 8; ++jj) {
        int idx = t + 256*jj;
        Xt[(idx>>7)*128 + (idx&127)] = av[jj];
      }
      __syncthreads();
      fma8x8(Xt, Wt, tn, tm, acc);
    }
  }
  #pragma unroll
  for (int mi = 0; mi < 8; ++mi) {
    const int o = o0 + tm + mi;
    const float* srow = src + srcb + (size_t)o*HW + hw0 + tn;
    const float bo = bias[o];
    float4 r0 = *(const float4*)&srow[0];
    float4 r1 = *(const float4*)&srow[4];
    float v0 = acc[mi][0]+bo+r0.x, v1 = acc[mi][1]+bo+r0.y;
    float v2 = acc[mi][2]+bo+r0.z, v3 = acc[mi][3]+bo+r0.w;
    float v4 = acc[mi][4]+bo+r1.x, v5 = acc[mi][5]+bo+r1.y;
    float v6 = acc[mi][6]+bo+r1.z, v7 = acc[mi][7]+bo+r1.w;
    uint4 pv;
    pv.x = pack2(v0,v1); pv.y = pack2(v2,v3);
    pv.z = pack2(v4,v5); pv.w = pack2(v6,v7);
    *(uint4*)&xout[(size_t)b*256*HW + (size_t)o*HW + hw0 + tn] = pv;
  }
}

// ---------------- GEMM: OUT[b,o,hw] = sum_c W[o,c] * X_bf16[b,c,hw] ----------------
template<bool F32OUT>
__global__ __launch_bounds__(256) void gemm_bf16A(const u16* __restrict__ X,
    const float* __restrict__ W, const float* __restrict__ bias,
    void* __restrict__ OUT, int O){
  __shared__ float Wt[16*128];
  __shared__ float Xt[16*128];
  const int t = threadIdx.x;
  const int hw0 = blockIdx.x * 128;
  const int o0  = blockIdx.y * 128;
  const int b   = blockIdx.z;
  const u16* Xb = X + (size_t)b * 256 * HW;
  float acc[8][8] = {};
  const int wo = t >> 1, wk = (t & 1) * 8;
  const int tn = (t & 15) * 8, tm = (t >> 4) * 8;
  const int kl0 = t >> 5,        n40 = t & 31;
  const int kl1 = (t+256) >> 5,  n41 = n40;

  for (int k0 = 0; k0 < 256; k0 += 16) {
    float4 wv0 = *(const float4*)&W[(o0+wo)*256 + k0 + wk];
    float4 wv1 = *(const float4*)&W[(o0+wo)*256 + k0 + wk + 4];
    ushort4 xa = *(const ushort4*)&Xb[(size_t)(k0+kl0)*HW + hw0 + n40*4];
    ushort4 xb = *(const ushort4*)&Xb[(size_t)(k0+kl1)*HW + hw0 + n41*4];
    __syncthreads();
    Wt[(wk+0)*128 + wo] = wv0.x; Wt[(wk+1)*128 + wo] = wv0.y;
    Wt[(wk+2)*128 + wo] = wv0.z; Wt[(wk+3)*128 + wo] = wv0.w;
    Wt[(wk+4)*128 + wo] = wv1.x; Wt[(wk+5)*128 + wo] = wv1.y;
    Wt[(wk+6)*128 + wo] = wv1.z; Wt[(wk+7)*128 + wo] = wv1.w;
    {
      float4 f; f.x = bf2f(xa.x); f.y = bf2f(xa.y); f.z = bf2f(xa.z); f.w = bf2f(xa.w);
      *(float4*)&Xt[kl0*128 + n40*4] = f;
      f.x = bf2f(xb.x); f.y = bf2f(xb.y); f.z = bf2f(xb.z); f.w = bf2f(xb.w);
      *(float4*)&Xt[kl1*128 + n41*4] = f;
    }
    __syncthreads();
    fma8x8(Xt, Wt, tn, tm, acc);
  }
  #pragma unroll
  for (int mi = 0; mi < 8; ++mi) {
    const int o = o0 + tm + mi;
    const size_t off = ((size_t)b*O + o)*HW + hw0 + tn;
    if constexpr (F32OUT) {
      const float bo = bias[o];
      float* op = (float*)OUT;
      float4 v0, v1;
      v0.x = acc[mi][0]+bo; v0.y = acc[mi][1]+bo; v0.z = acc[mi][2]+bo; v0.w = acc[mi][3]+bo;
      v1.x = acc[mi][4]+bo; v1.y = acc[mi][5]+bo; v1.z = acc[mi][6]+bo; v1.w = acc[mi][7]+bo;
      *(float4*)&op[off] = v0;
      *(float4*)&op[off+4] = v1;
    } else {
      u16* op = (u16*)OUT;
      uint4 pv;
      pv.x = pack2(acc[mi][0], acc[mi][1]); pv.y = pack2(acc[mi][2], acc[mi][3]);
      pv.z = pack2(acc[mi][4], acc[mi][5]); pv.w = pack2(acc[mi][6], acc[mi][7]);
      *(uint4*)&op[off] = pv;
    }
  }
}

// ---------------- softmax over spatial for k rows (in place, bf16) ----------------
__global__ __launch_bounds__(256) void softmax_k(u16* __restrict__ qkv){
  __shared__ float red[256];
  const int r = blockIdx.x;            // 0..4095
  const int b = r >> 8, ch = r & 255;
  u16* row = qkv + ((size_t)b*768 + 256 + ch) * HW;
  const int t = threadIdx.x;
  uint4 raw0 = *(const uint4*)&row[t*16];
  uint4 raw1 = *(const uint4*)&row[t*16 + 8];
  float v[16];
  unpack2(raw0.x, v[0], v[1]);  unpack2(raw0.y, v[2], v[3]);
  unpack2(raw0.z, v[4], v[5]);  unpack2(raw0.w, v[6], v[7]);
  unpack2(raw1.x, v[8], v[9]);  unpack2(raw1.y, v[10], v[11]);
  unpack2(raw1.z, v[12], v[13]); unpack2(raw1.w, v[14], v[15]);
  float m = v[0];
  #pragma unroll
  for (int i = 1; i < 16; ++i) m = fmaxf(m, v[i]);
  red[t] = m; __syncthreads();
  for (int s = 128; s > 0; s >>= 1){ if (t < s) red[t] = fmaxf(red[t], red[t+s]); __syncthreads(); }
  m = red[0]; __syncthreads();
  float sum = 0.f;
  #pragma unroll
  for (int i = 0; i < 16; ++i){ v[i] = __expf(v[i] - m); sum += v[i]; }
  red[t] = sum; __syncthreads();
  for (int s = 128; s > 0; s >>= 1){ if (t < s) red[t] = red[t] + red[t+s]; __syncthreads(); }
  const float inv = 1.0f / red[0];
  uint4 o0, o1;
  o0.x = pack2(v[0]*inv,  v[1]*inv);  o0.y = pack2(v[2]*inv,  v[3]*inv);
  o0.z = pack2(v[4]*inv,  v[5]*inv);  o0.w = pack2(v[6]*inv,  v[7]*inv);
  o1.x = pack2(v[8]*inv,  v[9]*inv);  o1.y = pack2(v[10]*inv, v[11]*inv);
  o1.z = pack2(v[12]*inv, v[13]*inv); o1.w = pack2(v[14]*inv, v[15]*inv);
  *(uint4*)&row[t*16]     = o0;
  *(uint4*)&row[t*16 + 8] = o1;
}

__global__ void zero_cl(float* __restrict__ cl){
  int i = blockIdx.x*256 + threadIdx.x;
  if (i < 128*32*32) cl[i] = 0.f;
}

// ---------------- content_lambda: cl[b',i,o] = sum_n kf[i,n]*v[o,n] ----------------
// 64-thread blocks; split-K over n (8 splits); XOR-swizzled LDS transpose; atomics.
__global__ __launch_bounds__(64) void lambda_kern(const u16* __restrict__ qkv,
                                                  float* __restrict__ cl){
  __shared__ float kT[64*32];
  __shared__ float vT[64*32];
  const int t  = threadIdx.x;
  const int bp = blockIdx.x;           // b' 0..127
  const int sp = blockIdx.y;           // split 0..7
  const int b = bp >> 3, h = bp & 7;
  const u16* kb = qkv + ((size_t)b*768 + 256 + h*32)*HW;
  const u16* vb = qkv + ((size_t)b*768 + 512 + h*32)*HW;
  const int li = t >> 1, half = t & 1;
  const int grp = t & 15, ig = grp & 3, og = grp >> 2, sl = t >> 4;
  float acc[8][8] = {};
  for (int c = 0; c < 8; ++c) {
    const int n0 = sp*512 + c*64;
    __syncthreads();
    #pragma unroll
    for (int j2 = 0; j2 < 4; ++j2) {
      const int nb = half*32 + j2*8;
      uint4 kr = *(const uint4*)&kb[(size_t)li*HW + n0 + nb];
      uint4 vr = *(const uint4*)&vb[(size_t)li*HW + n0 + nb];
      float kf[8], vv[8];
      unpack2(kr.x, kf[0], kf[1]); unpack2(kr.y, kf[2], kf[3]);
      unpack2(kr.z, kf[4], kf[5]); unpack2(kr.w, kf[6], kf[7]);
      unpack2(vr.x, vv[0], vv[1]); unpack2(vr.y, vv[2], vv[3]);
      unpack2(vr.z, vv[4], vv[5]); unpack2(vr.w, vv[6], vv[7]);
      #pragma unroll
      for (int e = 0; e < 8; ++e) {
        int n = nb + e;
        int swi = n*32 + ((((li>>2) ^ (n&7) ^ ((n>>3)&7)) & 7) << 2) + (li & 3);
        kT[swi] = kf[e]; vT[swi] = vv[e];
      }
    }
    __syncthreads();
    #pragma unroll
    for (int it = 0; it < 16; ++it) {
      const int n = sl*16 + it;
      const int x7 = (n&7) ^ ((n>>3)&7);
      float kf[8], vv[8];
      *(float4*)&kf[0] = *(const float4*)&kT[n*32 + ((((ig*2  ) ^ x7)&7)<<2)];
      *(float4*)&kf[4] = *(const float4*)&kT[n*32 + ((((ig*2+1) ^ x7)&7)<<2)];
      *(float4*)&vv[0] = *(const float4*)&vT[n*32 + ((((og*2  ) ^ x7)&7)<<2)];
      *(float4*)&vv[4] = *(const float4*)&vT[n*32 + ((((og*2+1) ^ x7)&7)<<2)];
      #pragma unroll
      for (int ii = 0; ii < 8; ++ii)
        #pragma unroll
        for (int oo = 0; oo < 8; ++oo)
          acc[ii][oo] = fmaf(kf[ii], vv[oo], acc[ii][oo]);
    }
  }
  #pragma unroll
  for (int ii = 0; ii < 8; ++ii)
    #pragma unroll
    for (int oo = 0; oo < 8; ++oo) {
      float s = acc[ii][oo];
      s += __shfl_xor(s, 16);
      s += __shfl_xor(s, 32);
      if (t < 16)
        atomicAdd(&cl[(size_t)bp*1024 + (ig*8+ii)*32 + og*8+oo], s);
    }
}

// ---------------- content: result[b',o,n] = sum_i (q[i,n]*scale) * cl[i,o] ----------
__global__ __launch_bounds__(256) void content_kern(const u16* __restrict__ qkv,
    const float* __restrict__ cl, u16* __restrict__ result){
  const int t = threadIdx.x;
  const int n = blockIdx.x * 256 + t;
  const int bp = blockIdx.y;
  const int b = bp >> 3, h = bp & 7;
  const u16* qb = qkv + ((size_t)b*768 + h*32)*HW;
  const float* clb = cl + (size_t)bp*1024;
  const float scale = 0.17677669529663687f;   // 32^-0.5
  float qv[32];
  #pragma unroll
  for (int i = 0; i < 32; ++i) qv[i] = bf2f(qb[(size_t)i*HW + n]) * scale;
  float acc[32] = {};
  #pragma unroll
  for (int i = 0; i < 32; ++i)
    #pragma unroll
    for (int o = 0; o < 32; ++o)
      acc[o] = fmaf(qv[i], clb[i*32+o], acc[o]);   // clb uniform -> s_loads
  u16* rb = result + ((size_t)b*256 + h*32)*HW;
  #pragma unroll
  for (int o = 0; o < 32; ++o) rb[(size_t)o*HW + n] = f2bf(acc[o]);
}

// ---------------- depthwise 5x5 pos_lambda; result += q * pos_lambda ----------------
__global__ __launch_bounds__(256) void combine_kern(const u16* __restrict__ qkv,
    const float* __restrict__ rel, u16* __restrict__ result){
  __shared__ float vt[8][36][40];
  const int t = threadIdx.x;
  const int tile = blockIdx.x;         // 0..3 (2x2 of 32x32)
  const int bp = blockIdx.y;
  const int b = bp >> 3, h = bp & 7;
  const int ty0 = (tile >> 1) * 32, tx0 = (tile & 1) * 32;
  const int px0 = (t & 7) * 4, py = t >> 3;
  const u16* vbase = qkv + ((size_t)b*768 + 512 + h*32)*HW;
  const u16* qbase = qkv + ((size_t)b*768 + h*32)*HW;
  u16* rbase = result + ((size_t)b*256 + h*32)*HW;
  for (int c4 = 0; c4 < 4; ++c4) {
    __syncthreads();
    for (int idx = t; idx < 8*36*36; idx += 256) {
      int ch = idx / 1296;
      int rem = idx - ch*1296;
      int rr = rem / 36;
      int cc = rem - rr*36;
      int ys = ty0 + rr - 2, xs = tx0 + cc - 2;
      float v = 0.f;
      if ((unsigned)ys < 64u && (unsigned)xs < 64u)
        v = bf2f(vbase[(size_t)(c4*8+ch)*HW + ys*64 + xs]);
      vt[ch][rr][cc] = v;
    }
    __syncthreads();
    for (int ol = 0; ol < 8; ++ol) {
      const int o = c4*8 + ol;
      const float* rb = rel + o*25;    // uniform -> s_loads
      float pos[4] = {0.f,0.f,0.f,0.f};
      #pragma unroll
      for (int dy = 0; dy < 5; ++dy) {
        float w[8];
        *(float4*)&w[0] = *(const float4*)&vt[ol][py+dy][px0];
        *(float4*)&w[4] = *(const float4*)&vt[ol][py+dy][px0+4];
        #pragma unroll
        for (int dx = 0; dx < 5; ++dx) {
          const float rw = rb[dy*5+dx];
          #pragma unroll
          for (int p = 0; p < 4; ++p) pos[p] = fmaf(rw, w[p+dx], pos[p]);
        }
      }
      const int hw = (ty0+py)*64 + tx0 + px0;
      ushort4 q4 = *(const ushort4*)&qbase[(size_t)o*HW + hw];
      ushort4 r4 = *(const ushort4*)&rbase[(size_t)o*HW + hw];
      ushort4 pv;
      pv.x = f2bf(bf2f(r4.x) + bf2f(q4.x)*pos[0]);
      pv.y = f2bf(bf2f(r4.y) + bf2f(q4.y)*pos[1]);
      pv.z = f2bf(bf2f(r4.z) + bf2f(q4.z)*pos[2]);
      pv.w = f2bf(bf2f(r4.w) + bf2f(q4.w)*pos[3]);
      *(ushort4*)&rbase[(size_t)o*HW + hw] = pv;
    }
  }
}

extern "C" void kernel_launch(void* const* d_in, const int* in_sizes, int n_in,
                              void* d_out, int out_size, void* d_ws, size_t ws_size,
                              hipStream_t stream) {
  const float* src   = (const float*)d_in[0];
  const float* rel   = (const float*)d_in[1];
  const float* qkv_w = (const float*)d_in[2];
  const float* cpe_w = (const float*)d_in[3];
  const float* cpe_b = (const float*)d_in[4];
  const float* out_w = (const float*)d_in[5];
  const float* out_b = (const float*)d_in[6];
  char* ws = (char*)d_ws;
  u16*   x   = (u16*)(ws);                       // conv output, later reused as "result"
  u16*   qkv = (u16*)(ws + 33554432);
  float* cl  = (float*)(ws + 134217728);
  float* wr  = (float*)(ws + 134742016);

  repack_cpe<<<dim3(2304), dim3(256), 0, stream>>>(cpe_w, wr);
  conv_cpe<<<dim3(32, 2, 16), dim3(256), 0, stream>>>(src, wr, cpe_b, x);
  gemm_bf16A<false><<<dim3(32, 6, 16), dim3(256), 0, stream>>>(x, qkv_w, nullptr, (void*)qkv, 768);
  softmax_k<<<dim3(4096), dim3(256), 0, stream>>>(qkv);
  zero_cl<<<dim3(512), dim3(256), 0, stream>>>(cl);
  lambda_kern<<<dim3(128, 8), dim3(64), 0, stream>>>(qkv, cl);
  content_kern<<<dim3(16, 128), dim3(256), 0, stream>>>(qkv, cl, x);   // x now = result
  combine_kern<<<dim3(4, 128), dim3(256), 0, stream>>>(qkv, rel, x);
  gemm_bf16A<true><<<dim3(32, 2, 16), dim3(256), 0, stream>>>(x, out_w, out_b, d_out, 256);
}

// Round 2
// 524.649 us; speedup vs baseline: 3.1629x; 3.1629x over previous
//
#include <hip/hip_runtime.h>

// MHConvAttention MFMA version. B=16, C=256, H=W=64, NH=8, hd=32, WS=5.
// All big GEMMs via mfma_f32_16x16x32_bf16, NHWC intermediates.
//
// Workspace layout (bytes), total 136,445,952 (<= 137,101,312 known-good):
//   [0)           qkv bf16 (65536,768)  100,663,296   ALIASED with:
//   [0)           xpad bf16 (16,66,66,256) 35,684,352 (dead after conv)
//   [100663296)   x / result bf16 (65536,256) 33,554,432
//   [134217728)   cl f32 (128,32,32)        524,288
//   [134742016)   wrb bf16 (9,256,256)    1,179,648
//   [135921664)   wq  bf16 (768,256)        393,216
//   [136314880)   wo  bf16 (256,256)        131,072

typedef unsigned short u16;
typedef __bf16 bf16x8 __attribute__((ext_vector_type(8)));
typedef float f32x4 __attribute__((ext_vector_type(4)));
#define HW 4096

__device__ __forceinline__ float bf2f(u16 u){
  unsigned v = ((unsigned)u) << 16;
  return __builtin_bit_cast(float, v);
}
__device__ __forceinline__ u16 f2bf(float f){
  unsigned u = __builtin_bit_cast(unsigned, f);
  u = u + 0x7fffu + ((u >> 16) & 1u);   // RNE
  return (u16)(u >> 16);
}
__device__ __forceinline__ unsigned pack2(float a, float b){
  return (unsigned)f2bf(a) | ((unsigned)f2bf(b) << 16);
}
__device__ __forceinline__ void unpack2(unsigned u, float& a, float& b){
  a = bf2f((u16)(u & 0xffffu)); b = bf2f((u16)(u >> 16));
}
__device__ __forceinline__ void unp8(uint4 r, float* v){
  unpack2(r.x, v[0], v[1]); unpack2(r.y, v[2], v[3]);
  unpack2(r.z, v[4], v[5]); unpack2(r.w, v[6], v[7]);
}
__device__ __forceinline__ int swz(int p){ return (p&3) ^ ((p>>2)&3); }

__device__ __forceinline__ void gl2lds16(const u16* g, u16* l){
  __builtin_amdgcn_global_load_lds((__attribute__((address_space(1))) void*)g,
                                   (__attribute__((address_space(3))) void*)l, 16, 0, 0);
}

// ---------------- zero xpad ----------------
__global__ void zero_pad(uint4* __restrict__ p){
  p[blockIdx.x*256 + threadIdx.x] = uint4{0,0,0,0};
}

// ---------------- src NCHW f32 -> xpad NHWC bf16 (66x66 zero-padded) ----------------
__global__ __launch_bounds__(256) void to_nhwc(const float* __restrict__ src,
                                               u16* __restrict__ xpad){
  __shared__ u16 sl[64*264];           // [pix][ch], row stride 264 els (528 B, 16B-mult)
  const int t = threadIdx.x, w = t>>6, lane = t&63;
  const int y = blockIdx.x, b = blockIdx.y;
  for (int cc = 0; cc < 64; ++cc){
    const int c = cc*4 + w;
    float v = src[((size_t)(b*256 + c))*HW + y*64 + lane];
    sl[lane*264 + c] = f2bf(v);
  }
  __syncthreads();
  #pragma unroll
  for (int i = 0; i < 8; ++i){
    int idx = t + 256*i;               // 2048 granules = 64 px * 32 granules
    int p = idx >> 5, g = idx & 31;
    uint4 v = *(const uint4*)&sl[p*264 + g*8];
    *(uint4*)&xpad[((size_t)b*4356 + (size_t)(y+1)*66 + (p+1))*256 + g*8] = v;
  }
}

// ---------------- repack all weights to bf16 ----------------
__global__ void repack_w(const float* __restrict__ cpe_w, const float* __restrict__ qkv_w,
                         const float* __restrict__ out_w, u16* __restrict__ wrb,
                         u16* __restrict__ wq, u16* __restrict__ wo){
  int idx = blockIdx.x*256 + threadIdx.x;       // 851968 total
  if (idx < 589824){
    int kk = idx >> 16, o = (idx >> 8) & 255, c = idx & 255;
    wrb[idx] = f2bf(cpe_w[((o*256 + c)*9) + kk]);
  } else if (idx < 786432){
    int j = idx - 589824;
    wq[j] = f2bf(qkv_w[j]);
  } else {
    int j = idx - 786432;
    wo[j] = f2bf(out_w[j]);
  }
}

// ---------------- CPE 3x3 conv: implicit GEMM, MFMA, + bias + residual -> x NHWC bf16
__global__ __launch_bounds__(256) void conv_mfma(const u16* __restrict__ xpad,
    const u16* __restrict__ wrb, const float* __restrict__ bias,
    u16* __restrict__ xout){
  __shared__ u16 As[4096];             // [128 px][32 k] bf16, 16B-granule XOR swizzle
  __shared__ u16 Bs[4096];             // [128 o ][32 k]
  const int t = threadIdx.x, w = t>>6, lane = t&63;
  const int pg = blockIdx.x*128;
  const int b = pg>>12, hw0 = pg&4095, y0 = hw0>>6;
  const int o0 = blockIdx.y*128;
  const size_t xb = (size_t)b*4356;
  // staging: thread t -> slot row sp=t>>2 (and sp+64), slot col t&3; logical k-chunk:
  const int sp = t>>2;
  const int cs = (t&3) ^ swz(sp);      // swz(sp)==swz(sp+64)
  const u16* agp0 = xpad + (xb + (size_t)(y0+1)*66 + sp + 1)*256 + cs*8;
  const u16* agp1 = agp0 + 66*256;     // second image row of the 128-px tile
  const u16* bgp0 = wrb + (size_t)(o0 + sp)*256 + cs*8;
  const u16* bgp1 = bgp0 + 64*256;
  const int wm = w&1, wn = w>>1;
  int a_off[4], b_off[4];
  #pragma unroll
  for (int i = 0; i < 4; ++i){
    int p = wm*64 + i*16 + (lane&15);
    a_off[i] = p*32 + ((((lane>>4) ^ swz(p)) & 3) << 3);
    int r = wn*64 + i*16 + (lane&15);
    b_off[i] = r*32 + ((((lane>>4) ^ swz(r)) & 3) << 3);
  }
  f32x4 acc[4][4];
  #pragma unroll
  for (int i=0;i<4;++i)
    #pragma unroll
    for (int j=0;j<4;++j) acc[i][j] = f32x4{0.f,0.f,0.f,0.f};

  for (int kk = 0; kk < 9; ++kk){
    const int toff = ((kk/3 - 1)*66 + (kk%3 - 1))*256;
    const u16* a0 = agp0 + toff; const u16* a1 = agp1 + toff;
    const u16* b0 = bgp0 + kk*65536; const u16* b1 = bgp1 + kk*65536;
    for (int c0 = 0; c0 < 256; c0 += 32){
      __syncthreads();
      gl2lds16(a0 + c0, &As[t*8]);
      gl2lds16(a1 + c0, &As[2048 + t*8]);
      gl2lds16(b0 + c0, &Bs[t*8]);
      gl2lds16(b1 + c0, &Bs[2048 + t*8]);
      __syncthreads();
      bf16x8 af[4], bfr[4];
      #pragma unroll
      for (int i = 0; i < 4; ++i){
        af[i]  = __builtin_bit_cast(bf16x8, *(const uint4*)&As[a_off[i]]);
        bfr[i] = __builtin_bit_cast(bf16x8, *(const uint4*)&Bs[b_off[i]]);
      }
      #pragma unroll
      for (int mt = 0; mt < 4; ++mt)
        #pragma unroll
        for (int nt = 0; nt < 4; ++nt)
          acc[mt][nt] = __builtin_amdgcn_mfma_f32_16x16x32_bf16(af[mt], bfr[nt], acc[mt][nt], 0,0,0);
    }
  }
  const int col = lane&15, row_l = (lane>>4)*4;
  #pragma unroll
  for (int nt = 0; nt < 4; ++nt){
    const int och = o0 + wn*64 + nt*16 + col;
    const float bo = bias[och];
    #pragma unroll
    for (int mt = 0; mt < 4; ++mt){
      const int pl = wm*64 + mt*16 + row_l;
      #pragma unroll
      for (int r = 0; r < 4; ++r){
        const int hw = hw0 + pl + r;
        const int y = hw>>6, x = hw&63;
        const float res = bf2f(xpad[(xb + (size_t)(y+1)*66 + x + 1)*256 + och]);
        xout[(size_t)(pg + pl + r)*256 + och] = f2bf(acc[mt][nt][r] + bo + res);
      }
    }
  }
}

// ---------------- generic K=256 MFMA GEMM: out[n][o] = act[n][:] . wt[o][:] ----------------
template<int NO, bool F32OUT>
__global__ __launch_bounds__(256) void gemm_mfma(const u16* __restrict__ act,
    const u16* __restrict__ wt, const float* __restrict__ bias, void* __restrict__ out){
  __shared__ u16 As[4096];
  __shared__ u16 Bs[4096];
  const int t = threadIdx.x, w = t>>6, lane = t&63;
  const int pg = blockIdx.x*128, o0 = blockIdx.y*128;
  const int sp = t>>2;
  const int cs = (t&3) ^ swz(sp);
  const u16* agp0 = act + (size_t)(pg + sp)*256 + cs*8;
  const u16* agp1 = agp0 + 64*256;
  const u16* bgp0 = wt + (size_t)(o0 + sp)*256 + cs*8;
  const u16* bgp1 = bgp0 + 64*256;
  const int wm = w&1, wn = w>>1;
  int a_off[4], b_off[4];
  #pragma unroll
  for (int i = 0; i < 4; ++i){
    int p = wm*64 + i*16 + (lane&15);
    a_off[i] = p*32 + ((((lane>>4) ^ swz(p)) & 3) << 3);
    int r = wn*64 + i*16 + (lane&15);
    b_off[i] = r*32 + ((((lane>>4) ^ swz(r)) & 3) << 3);
  }
  f32x4 acc[4][4];
  #pragma unroll
  for (int i=0;i<4;++i)
    #pragma unroll
    for (int j=0;j<4;++j) acc[i][j] = f32x4{0.f,0.f,0.f,0.f};

  for (int c0 = 0; c0 < 256; c0 += 32){
    __syncthreads();
    gl2lds16(agp0 + c0, &As[t*8]);
    gl2lds16(agp1 + c0, &As[2048 + t*8]);
    gl2lds16(bgp0 + c0, &Bs[t*8]);
    gl2lds16(bgp1 + c0, &Bs[2048 + t*8]);
    __syncthreads();
    bf16x8 af[4], bfr[4];
    #pragma unroll
    for (int i = 0; i < 4; ++i){
      af[i]  = __builtin_bit_cast(bf16x8, *(const uint4*)&As[a_off[i]]);
      bfr[i] = __builtin_bit_cast(bf16x8, *(const uint4*)&Bs[b_off[i]]);
    }
    #pragma unroll
    for (int mt = 0; mt < 4; ++mt)
      #pragma unroll
      for (int nt = 0; nt < 4; ++nt)
        acc[mt][nt] = __builtin_amdgcn_mfma_f32_16x16x32_bf16(af[mt], bfr[nt], acc[mt][nt], 0,0,0);
  }
  const int col = lane&15, row_l = (lane>>4)*4;
  if constexpr (F32OUT){
    const int b = pg>>12, hw0 = pg&4095;
    float* op = (float*)out;
    #pragma unroll
    for (int nt = 0; nt < 4; ++nt){
      const int och = o0 + wn*64 + nt*16 + col;
      const float bo = bias[och];
      #pragma unroll
      for (int mt = 0; mt < 4; ++mt){
        const int pl = wm*64 + mt*16 + row_l;
        float4 v;
        v.x = acc[mt][nt][0]+bo; v.y = acc[mt][nt][1]+bo;
        v.z = acc[mt][nt][2]+bo; v.w = acc[mt][nt][3]+bo;
        *(float4*)&op[((size_t)b*256 + och)*HW + hw0 + pl] = v;
      }
    }
  } else {
    u16* op = (u16*)out;
    #pragma unroll
    for (int nt = 0; nt < 4; ++nt){
      const int och = o0 + wn*64 + nt*16 + col;
      #pragma unroll
      for (int mt = 0; mt < 4; ++mt){
        const int pl = wm*64 + mt*16 + row_l;
        #pragma unroll
        for (int r = 0; r < 4; ++r)
          op[(size_t)(pg + pl + r)*NO + och] = f2bf(acc[mt][nt][r]);
      }
    }
  }
}

// ---------------- softmax over spatial (4096) per (b, k-channel), NHWC in-place ----------------
__global__ __launch_bounds__(256) void softmax_k(u16* __restrict__ qkv){
  __shared__ float red[256][9];
  const int t = threadIdx.x;
  const int b = blockIdx.x;
  const int g = t&3, psub = t>>2;
  const int ch0 = blockIdx.y*32 + g*8;
  u16* base = qkv + ((size_t)b*HW)*768 + 256 + ch0;
  float mx[8];
  #pragma unroll
  for (int j=0;j<8;++j) mx[j] = -1e30f;
  for (int it = 0; it < 64; ++it){
    int p = it*64 + psub;
    uint4 r = *(const uint4*)&base[(size_t)p*768];
    float v[8]; unp8(r, v);
    #pragma unroll
    for (int j=0;j<8;++j) mx[j] = fmaxf(mx[j], v[j]);
  }
  #pragma unroll
  for (int j=0;j<8;++j) red[t][j] = mx[j];
  __syncthreads();
  for (int s = 128; s >= 4; s >>= 1){
    if (t < s){ for (int j=0;j<8;++j) red[t][j] = fmaxf(red[t][j], red[t+s][j]); }
    __syncthreads();
  }
  float m8[8];
  #pragma unroll
  for (int j=0;j<8;++j) m8[j] = red[g][j];
  __syncthreads();
  float sm[8];
  #pragma unroll
  for (int j=0;j<8;++j) sm[j] = 0.f;
  for (int it = 0; it < 64; ++it){
    int p = it*64 + psub;
    uint4 r = *(const uint4*)&base[(size_t)p*768];
    float v[8]; unp8(r, v);
    #pragma unroll
    for (int j=0;j<8;++j) sm[j] += __expf(v[j] - m8[j]);
  }
  #pragma unroll
  for (int j=0;j<8;++j) red[t][j] = sm[j];
  __syncthreads();
  for (int s = 128; s >= 4; s >>= 1){
    if (t < s){ for (int j=0;j<8;++j) red[t][j] += red[t+s][j]; }
    __syncthreads();
  }
  float inv[8];
  #pragma unroll
  for (int j=0;j<8;++j) inv[j] = 1.0f / red[g][j];
  for (int it = 0; it < 64; ++it){
    int p = it*64 + psub;
    uint4 r = *(const uint4*)&base[(size_t)p*768];
    float v[8]; unp8(r, v);
    uint4 o_;
    o_.x = pack2(__expf(v[0]-m8[0])*inv[0], __expf(v[1]-m8[1])*inv[1]);
    o_.y = pack2(__expf(v[2]-m8[2])*inv[2], __expf(v[3]-m8[3])*inv[3]);
    o_.z = pack2(__expf(v[4]-m8[4])*inv[4], __expf(v[5]-m8[5])*inv[5]);
    o_.w = pack2(__expf(v[6]-m8[6])*inv[6], __expf(v[7]-m8[7])*inv[7]);
    *(uint4*)&base[(size_t)p*768] = o_;
  }
}

__global__ void zero_cl(float* __restrict__ cl){
  cl[blockIdx.x*256 + threadIdx.x] = 0.f;
}

// ---------------- content_lambda: cl[b',i,o] = sum_n kf[n][i]*v[n][o] ----------------
__global__ __launch_bounds__(64) void lambda_kern(const u16* __restrict__ qkv,
                                                  float* __restrict__ cl){
  __shared__ float Kl[64*36];
  __shared__ float Vl[64*36];
  const int t = threadIdx.x;
  const int bp = blockIdx.x, split = blockIdx.y;
  const int b = bp>>3, h = bp&7;
  const int ig = t&7, og = t>>3;
  float acc[4][4];
  #pragma unroll
  for (int i=0;i<4;++i)
    #pragma unroll
    for (int j=0;j<4;++j) acc[i][j] = 0.f;
  for (int chunk = 0; chunk < 8; ++chunk){
    const int n = split*512 + chunk*64 + t;
    const u16* kp = qkv + (size_t)(b*HW + n)*768 + 256 + h*32;
    const u16* vp = kp + 256;
    uint4 k4[4], v4[4];
    #pragma unroll
    for (int q=0;q<4;++q){ k4[q] = ((const uint4*)kp)[q]; v4[q] = ((const uint4*)vp)[q]; }
    __syncthreads();
    #pragma unroll
    for (int q=0;q<4;++q){
      float kv[8], vv[8]; unp8(k4[q], kv); unp8(v4[q], vv);
      *(float4*)&Kl[t*36 + q*8]     = float4{kv[0],kv[1],kv[2],kv[3]};
      *(float4*)&Kl[t*36 + q*8 + 4] = float4{kv[4],kv[5],kv[6],kv[7]};
      *(float4*)&Vl[t*36 + q*8]     = float4{vv[0],vv[1],vv[2],vv[3]};
      *(float4*)&Vl[t*36 + q*8 + 4] = float4{vv[4],vv[5],vv[6],vv[7]};
    }
    __syncthreads();
    for (int p = 0; p < 64; ++p){
      float4 kf = *(const float4*)&Kl[p*36 + ig*4];
      float4 vf = *(const float4*)&Vl[p*36 + og*4];
      float kfa[4] = {kf.x,kf.y,kf.z,kf.w};
      float vfa[4] = {vf.x,vf.y,vf.z,vf.w};
      #pragma unroll
      for (int i=0;i<4;++i)
        #pragma unroll
        for (int j=0;j<4;++j) acc[i][j] = fmaf(kfa[i], vfa[j], acc[i][j]);
    }
  }
  #pragma unroll
  for (int i=0;i<4;++i)
    #pragma unroll
    for (int j=0;j<4;++j)
      atomicAdd(&cl[(size_t)bp*1024 + (ig*4+i)*32 + og*4+j], acc[i][j]);
}

// ---------------- fused content + depthwise-5x5 pos-lambda + combine -> result NHWC ----------------
__global__ __launch_bounds__(256) void content_combine(const u16* __restrict__ qkv,
    const float* __restrict__ cl, const float* __restrict__ rel, u16* __restrict__ res){
  __shared__ u16 vt[12800];            // [20*20 halo px][32 ch] bf16, swizzled granules
  __shared__ float cls[1024];          // cl * scale, [i][o]
  __shared__ float relT[800];          // [tap][ch]
  const int t = threadIdx.x;
  const int tile = blockIdx.x, h = blockIdx.y, b = blockIdx.z;
  const int x0 = (tile&3)*16, y0 = (tile>>2)*16;
  for (int idx = t; idx < 1024; idx += 256)
    cls[idx] = cl[(size_t)(b*8+h)*1024 + idx] * 0.17677669529663687f;
  for (int idx = t; idx < 800; idx += 256){
    int tap = idx>>5, ch = idx&31;
    relT[idx] = rel[ch*25 + tap];
  }
  #pragma unroll
  for (int i = 0; i < 7; ++i){
    int idx = t + 256*i;
    if (idx < 1600){
      int hp = idx>>2, g = idx&3;
      int hy = hp/20, hx = hp - hy*20;
      int y = y0 + hy - 2, x = x0 + hx - 2;
      uint4 v = uint4{0,0,0,0};
      if ((unsigned)y < 64u && (unsigned)x < 64u)
        v = *(const uint4*)&qkv[(size_t)(b*HW + y*64 + x)*768 + 512 + h*32 + g*8];
      *(uint4*)&vt[hp*32 + ((g ^ (hx&3))<<3)] = v;
    }
  }
  __syncthreads();
  const int py = t>>4, px = t&15;
  const int pix = b*HW + (y0+py)*64 + x0 + px;
  const u16* qp = qkv + (size_t)pix*768 + h*32;
  float qv[32];
  {
    uint4 q0 = ((const uint4*)qp)[0], q1 = ((const uint4*)qp)[1];
    uint4 q2 = ((const uint4*)qp)[2], q3 = ((const uint4*)qp)[3];
    unp8(q0, qv); unp8(q1, qv+8); unp8(q2, qv+16); unp8(q3, qv+24);
  }
  float outv[32];
  #pragma unroll
  for (int j=0;j<32;++j) outv[j] = 0.f;
  for (int i = 0; i < 32; ++i){
    const float qi = qv[i];
    #pragma unroll
    for (int g = 0; g < 8; ++g){
      float4 c4 = *(const float4*)&cls[i*32 + g*4];
      outv[g*4+0] = fmaf(qi, c4.x, outv[g*4+0]);
      outv[g*4+1] = fmaf(qi, c4.y, outv[g*4+1]);
      outv[g*4+2] = fmaf(qi, c4.z, outv[g*4+2]);
      outv[g*4+3] = fmaf(qi, c4.w, outv[g*4+3]);
    }
  }
  #pragma unroll
  for (int chg = 0; chg < 4; ++chg){
    float pos[8];
    #pragma unroll
    for (int j=0;j<8;++j) pos[j] = 0.f;
    #pragma unroll
    for (int dy = 0; dy < 5; ++dy)
      #pragma unroll
      for (int dx = 0; dx < 5; ++dx){
        int hx = px + dx;
        uint4 v4 = *(const uint4*)&vt[((py+dy)*20 + hx)*32 + ((chg ^ (hx&3))<<3)];
        float vv[8]; unp8(v4, vv);
        float4 r0 = *(const float4*)&relT[(dy*5+dx)*32 + chg*8];
        float4 r1 = *(const float4*)&relT[(dy*5+dx)*32 + chg*8 + 4];
        pos[0]=fmaf(r0.x, vv[0], pos[0]); pos[1]=fmaf(r0.y, vv[1], pos[1]);
        pos[2]=fmaf(r0.z, vv[2], pos[2]); pos[3]=fmaf(r0.w, vv[3], pos[3]);
        pos[4]=fmaf(r1.x, vv[4], pos[4]); pos[5]=fmaf(r1.y, vv[5], pos[5]);
        pos[6]=fmaf(r1.z, vv[6], pos[6]); pos[7]=fmaf(r1.w, vv[7], pos[7]);
      }
    #pragma unroll
    for (int j=0;j<8;++j) outv[chg*8+j] = fmaf(qv[chg*8+j], pos[j], outv[chg*8+j]);
  }
  u16* rp = res + (size_t)pix*256 + h*32;
  #pragma unroll
  for (int g = 0; g < 4; ++g){
    uint4 o_;
    o_.x = pack2(outv[g*8+0], outv[g*8+1]);
    o_.y = pack2(outv[g*8+2], outv[g*8+3]);
    o_.z = pack2(outv[g*8+4], outv[g*8+5]);
    o_.w = pack2(outv[g*8+6], outv[g*8+7]);
    ((uint4*)rp)[g] = o_;
  }
}

extern "C" void kernel_launch(void* const* d_in, const int* in_sizes, int n_in,
                              void* d_out, int out_size, void* d_ws, size_t ws_size,
                              hipStream_t stream) {
  const float* src   = (const float*)d_in[0];
  const float* rel   = (const float*)d_in[1];
  const float* qkv_w = (const float*)d_in[2];
  const float* cpe_w = (const float*)d_in[3];
  const float* cpe_b = (const float*)d_in[4];
  const float* out_w = (const float*)d_in[5];
  const float* out_b = (const float*)d_in[6];
  char* ws = (char*)d_ws;
  u16*   qkv  = (u16*)(ws);                    // 100.7 MB
  u16*   xpad = (u16*)(ws);                    // aliased (dead after conv)
  u16*   xbuf = (u16*)(ws + 100663296);        // conv out, later result
  float* cl   = (float*)(ws + 134217728);
  u16*   wrb  = (u16*)(ws + 134742016);
  u16*   wq   = (u16*)(ws + 135921664);
  u16*   wo   = (u16*)(ws + 136314880);

  zero_pad<<<dim3(8712), dim3(256), 0, stream>>>((uint4*)xpad);
  to_nhwc<<<dim3(64, 16), dim3(256), 0, stream>>>(src, xpad);
  repack_w<<<dim3(3328), dim3(256), 0, stream>>>(cpe_w, qkv_w, out_w, wrb, wq, wo);
  conv_mfma<<<dim3(512, 2), dim3(256), 0, stream>>>(xpad, wrb, cpe_b, xbuf);
  gemm_mfma<768,false><<<dim3(512, 6), dim3(256), 0, stream>>>(xbuf, wq, nullptr, (void*)qkv);
  softmax_k<<<dim3(16, 8), dim3(256), 0, stream>>>(qkv);
  zero_cl<<<dim3(512), dim3(256), 0, stream>>>(cl);
  lambda_kern<<<dim3(128, 8), dim3(64), 0, stream>>>(qkv, cl);
  content_combine<<<dim3(16, 8, 16), dim3(256), 0, stream>>>(qkv, cl, rel, xbuf);
  gemm_mfma<256,true><<<dim3(512, 2), dim3(256), 0, stream>>>(xbuf, wo, out_b, d_out);
}

// Round 3
// 468.063 us; speedup vs baseline: 3.5453x; 1.1209x over previous
//
#include <hip/hip_runtime.h>

// MHConvAttention MFMA v3. B=16, C=256, H=W=64, NH=8, hd=32, WS=5.
// NHWC intermediates; mfma_f32_16x16x32_bf16; swapped-operand epilogues for
// channel-contiguous bf16 stores; softmax folded into lambda (exp + row sums).
//
// Workspace layout (bytes), total 136,462,336 (<= 137,101,312 known-good):
//   [0)           qkv bf16 (65536,768)  100,663,296   ALIASED with:
//   [0)           xpad bf16 (16,66,66,256) 35,684,352 (dead after conv)
//   [100663296)   x / result bf16 (65536,256) 33,554,432
//   [134217728)   cl f32 (128,32,32)        524,288
//   [134742016)   S  f32 (128,32)            16,384
//   [134758400)   wrb bf16 (9,256,256)    1,179,648
//   [135938048)   wq  bf16 (768,256)        393,216
//   [136331264)   wo  bf16 (256,256)        131,072

typedef unsigned short u16;
typedef __bf16 bf16x8 __attribute__((ext_vector_type(8)));
typedef float f32x4 __attribute__((ext_vector_type(4)));
#define HW 4096

__device__ __forceinline__ float bf2f(u16 u){
  unsigned v = ((unsigned)u) << 16;
  return __builtin_bit_cast(float, v);
}
__device__ __forceinline__ u16 f2bf(float f){
  unsigned u = __builtin_bit_cast(unsigned, f);
  u = u + 0x7fffu + ((u >> 16) & 1u);   // RNE
  return (u16)(u >> 16);
}
__device__ __forceinline__ unsigned pack2(float a, float b){
  return (unsigned)f2bf(a) | ((unsigned)f2bf(b) << 16);
}
__device__ __forceinline__ void unpack2(unsigned u, float& a, float& b){
  a = bf2f((u16)(u & 0xffffu)); b = bf2f((u16)(u >> 16));
}
__device__ __forceinline__ void unp8(uint4 r, float* v){
  unpack2(r.x, v[0], v[1]); unpack2(r.y, v[2], v[3]);
  unpack2(r.z, v[4], v[5]); unpack2(r.w, v[6], v[7]);
}
__device__ __forceinline__ int swz(int p){ return (p&3) ^ ((p>>2)&3); }

__device__ __forceinline__ void gl2lds16(const u16* g, u16* l){
  __builtin_amdgcn_global_load_lds((__attribute__((address_space(1))) void*)g,
                                   (__attribute__((address_space(3))) void*)l, 16, 0, 0);
}

// ---------------- zero only the 1-px border of xpad ----------------
__global__ void zero_border(u16* __restrict__ xpad){
  int idx = blockIdx.x*256 + threadIdx.x;   // 133120 granules
  int g = idx & 31;
  int p = idx >> 5;                         // border px 0..4159
  int b = p / 260; int r = p - b*260;
  int y, x;
  if (r < 66)      { y = 0;      x = r; }
  else if (r < 132){ y = 65;     x = r-66; }
  else if (r < 196){ y = r-131;  x = 0; }
  else             { y = r-195;  x = 65; }
  *(uint4*)&xpad[((size_t)b*4356 + (size_t)y*66 + x)*256 + g*8] = uint4{0,0,0,0};
}

// ---------------- src NCHW f32 -> xpad NHWC bf16 (66x66, interior) ----------------
__global__ __launch_bounds__(256) void to_nhwc(const float* __restrict__ src,
                                               u16* __restrict__ xpad){
  __shared__ u16 sl[64*264];
  const int t = threadIdx.x, w = t>>6, lane = t&63;
  const int y = blockIdx.x, b = blockIdx.y;
  for (int cc = 0; cc < 64; ++cc){
    const int c = cc*4 + w;
    float v = src[((size_t)(b*256 + c))*HW + y*64 + lane];
    sl[lane*264 + c] = f2bf(v);
  }
  __syncthreads();
  #pragma unroll
  for (int i = 0; i < 8; ++i){
    int idx = t + 256*i;
    int p = idx >> 5, g = idx & 31;
    uint4 v = *(const uint4*)&sl[p*264 + g*8];
    *(uint4*)&xpad[((size_t)b*4356 + (size_t)(y+1)*66 + (p+1))*256 + g*8] = v;
  }
}

// ---------------- repack all weights to bf16 ----------------
__global__ void repack_w(const float* __restrict__ cpe_w, const float* __restrict__ qkv_w,
                         const float* __restrict__ out_w, u16* __restrict__ wrb,
                         u16* __restrict__ wq, u16* __restrict__ wo){
  int idx = blockIdx.x*256 + threadIdx.x;
  if (idx < 589824){
    int kk = idx >> 16, o = (idx >> 8) & 255, c = idx & 255;
    wrb[idx] = f2bf(cpe_w[((o*256 + c)*9) + kk]);
  } else if (idx < 786432){
    int j = idx - 589824;
    wq[j] = f2bf(qkv_w[j]);
  } else {
    int j = idx - 786432;
    wo[j] = f2bf(out_w[j]);
  }
}

// ---------------- CPE 3x3 conv: implicit GEMM, swapped-operand MFMA ----------------
__global__ __launch_bounds__(256) void conv_mfma(const u16* __restrict__ xpad,
    const u16* __restrict__ wrb, const float* __restrict__ bias,
    u16* __restrict__ xout){
  __shared__ u16 As[4096];             // pixels [128 px][32 k]
  __shared__ u16 Bs[4096];             // weights [128 o][32 k]
  const int t = threadIdx.x, w = t>>6, lane = t&63;
  // XCD swizzle: {2 o-tiles of same n-block} -> same XCD
  const int idx = blockIdx.x;          // 0..1023
  const int x8 = idx&7, q = idx>>3;
  const int ot = q & 1, nb = (q>>1)*8 + x8;
  const int pg = nb*128;
  const int b = pg>>12, hw0 = pg&4095, y0 = hw0>>6;
  const int o0 = ot*128;
  const size_t xb = (size_t)b*4356;
  const int sp = t>>2;
  const int cs = (t&3) ^ swz(sp);
  const u16* agp0 = xpad + (xb + (size_t)(y0+1)*66 + sp + 1)*256 + cs*8;
  const u16* agp1 = agp0 + 66*256;
  const u16* bgp0 = wrb + (size_t)(o0 + sp)*256 + cs*8;
  const u16* bgp1 = bgp0 + 64*256;
  const int wm = w&1, wn = w>>1;
  int a_off[4], b_off[4];
  #pragma unroll
  for (int i = 0; i < 4; ++i){
    int p = wm*64 + i*16 + (lane&15);
    a_off[i] = p*32 + ((((lane>>4) ^ swz(p)) & 3) << 3);
    int r = wn*64 + i*16 + (lane&15);
    b_off[i] = r*32 + ((((lane>>4) ^ swz(r)) & 3) << 3);
  }
  f32x4 acc[4][4];
  #pragma unroll
  for (int i=0;i<4;++i)
    #pragma unroll
    for (int j=0;j<4;++j) acc[i][j] = f32x4{0.f,0.f,0.f,0.f};

  for (int c0 = 0; c0 < 256; c0 += 32){
    for (int kk = 0; kk < 9; ++kk){
      const int toff = ((kk/3 - 1)*66 + (kk%3 - 1))*256;
      __syncthreads();
      gl2lds16(agp0 + toff + c0, &As[t*8]);
      gl2lds16(agp1 + toff + c0, &As[2048 + t*8]);
      gl2lds16(bgp0 + kk*65536 + c0, &Bs[t*8]);
      gl2lds16(bgp1 + kk*65536 + c0, &Bs[2048 + t*8]);
      __syncthreads();
      bf16x8 af[4], bfr[4];
      #pragma unroll
      for (int i = 0; i < 4; ++i){
        af[i]  = __builtin_bit_cast(bf16x8, *(const uint4*)&As[a_off[i]]);
        bfr[i] = __builtin_bit_cast(bf16x8, *(const uint4*)&Bs[b_off[i]]);
      }
      #pragma unroll
      for (int mt = 0; mt < 4; ++mt)
        #pragma unroll
        for (int nt = 0; nt < 4; ++nt)   // A=weights, B=pixels -> D[m=och][n=px]
          acc[mt][nt] = __builtin_amdgcn_mfma_f32_16x16x32_bf16(bfr[nt], af[mt], acc[mt][nt], 0,0,0);
    }
  }
  // epilogue: lane holds 4 consecutive och at one px -> 8-B stores
  #pragma unroll
  for (int nt = 0; nt < 4; ++nt){
    const int och4 = o0 + wn*64 + nt*16 + (lane>>4)*4;
    float4 b4 = *(const float4*)&bias[och4];
    #pragma unroll
    for (int mt = 0; mt < 4; ++mt){
      const int px = wm*64 + mt*16 + (lane&15);
      const int hw = hw0 + px;
      const int y = hw>>6, x = hw&63;
      ushort4 r4 = *(const ushort4*)&xpad[(xb + (size_t)(y+1)*66 + x + 1)*256 + och4];
      ushort4 s;
      s.x = f2bf(acc[mt][nt][0] + b4.x + bf2f(r4.x));
      s.y = f2bf(acc[mt][nt][1] + b4.y + bf2f(r4.y));
      s.z = f2bf(acc[mt][nt][2] + b4.z + bf2f(r4.z));
      s.w = f2bf(acc[mt][nt][3] + b4.w + bf2f(r4.w));
      *(ushort4*)&xout[(size_t)(pg + px)*256 + och4] = s;
    }
  }
}

// ---------------- K=256 MFMA GEMM. NOT o-tiles per n-block; XCD-swizzled grid. ----
// F32OUT=false: swapped operands, NHWC bf16 out. F32OUT=true: NCHW f32 out + bias.
template<int NO, int NOT, bool F32OUT>
__global__ __launch_bounds__(256) void gemm_mfma(const u16* __restrict__ act,
    const u16* __restrict__ wt, const float* __restrict__ bias, void* __restrict__ out){
  __shared__ u16 As[4096];
  __shared__ u16 Bs[4096];
  const int t = threadIdx.x, w = t>>6, lane = t&63;
  const int idx = blockIdx.x;
  const int x8 = idx&7, q = idx>>3;
  const int ot = q % NOT, nb = (q / NOT)*8 + x8;
  const int pg = nb*128, o0 = ot*128;
  const int sp = t>>2;
  const int cs = (t&3) ^ swz(sp);
  const u16* agp0 = act + (size_t)(pg + sp)*256 + cs*8;
  const u16* agp1 = agp0 + 64*256;
  const u16* bgp0 = wt + (size_t)(o0 + sp)*256 + cs*8;
  const u16* bgp1 = bgp0 + 64*256;
  const int wm = w&1, wn = w>>1;
  int a_off[4], b_off[4];
  #pragma unroll
  for (int i = 0; i < 4; ++i){
    int p = wm*64 + i*16 + (lane&15);
    a_off[i] = p*32 + ((((lane>>4) ^ swz(p)) & 3) << 3);
    int r = wn*64 + i*16 + (lane&15);
    b_off[i] = r*32 + ((((lane>>4) ^ swz(r)) & 3) << 3);
  }
  f32x4 acc[4][4];
  #pragma unroll
  for (int i=0;i<4;++i)
    #pragma unroll
    for (int j=0;j<4;++j) acc[i][j] = f32x4{0.f,0.f,0.f,0.f};

  for (int c0 = 0; c0 < 256; c0 += 32){
    __syncthreads();
    gl2lds16(agp0 + c0, &As[t*8]);
    gl2lds16(agp1 + c0, &As[2048 + t*8]);
    gl2lds16(bgp0 + c0, &Bs[t*8]);
    gl2lds16(bgp1 + c0, &Bs[2048 + t*8]);
    __syncthreads();
    bf16x8 af[4], bfr[4];
    #pragma unroll
    for (int i = 0; i < 4; ++i){
      af[i]  = __builtin_bit_cast(bf16x8, *(const uint4*)&As[a_off[i]]);
      bfr[i] = __builtin_bit_cast(bf16x8, *(const uint4*)&Bs[b_off[i]]);
    }
    #pragma unroll
    for (int mt = 0; mt < 4; ++mt)
      #pragma unroll
      for (int nt = 0; nt < 4; ++nt){
        if constexpr (F32OUT)
          acc[mt][nt] = __builtin_amdgcn_mfma_f32_16x16x32_bf16(af[mt], bfr[nt], acc[mt][nt], 0,0,0);
        else
          acc[mt][nt] = __builtin_amdgcn_mfma_f32_16x16x32_bf16(bfr[nt], af[mt], acc[mt][nt], 0,0,0);
      }
  }
  if constexpr (F32OUT){
    const int col = lane&15, row_l = (lane>>4)*4;
    const int b = pg>>12, hw0 = pg&4095;
    float* op = (float*)out;
    #pragma unroll
    for (int nt = 0; nt < 4; ++nt){
      const int och = o0 + wn*64 + nt*16 + col;
      const float bo = bias[och];
      #pragma unroll
      for (int mt = 0; mt < 4; ++mt){
        const int pl = wm*64 + mt*16 + row_l;
        float4 v;
        v.x = acc[mt][nt][0]+bo; v.y = acc[mt][nt][1]+bo;
        v.z = acc[mt][nt][2]+bo; v.w = acc[mt][nt][3]+bo;
        *(float4*)&op[((size_t)b*256 + och)*HW + hw0 + pl] = v;
      }
    }
  } else {
    u16* op = (u16*)out;
    #pragma unroll
    for (int nt = 0; nt < 4; ++nt){
      const int och4 = o0 + wn*64 + nt*16 + (lane>>4)*4;
      #pragma unroll
      for (int mt = 0; mt < 4; ++mt){
        const int px = wm*64 + mt*16 + (lane&15);
        ushort4 s;
        s.x = f2bf(acc[mt][nt][0]); s.y = f2bf(acc[mt][nt][1]);
        s.z = f2bf(acc[mt][nt][2]); s.w = f2bf(acc[mt][nt][3]);
        *(ushort4*)&op[(size_t)(pg + px)*NO + och4] = s;
      }
    }
  }
}

__global__ void zero_cl(float* __restrict__ cl){
  cl[blockIdx.x*256 + threadIdx.x] = 0.f;   // zeros cl (131072) + S (4096)
}

// ---------------- lambda: cl'[b',i,o] = sum_n exp(k[n][i])*v[n][o]; S[b',i] = sum_n exp ----
__global__ __launch_bounds__(64) void lambda_kern(const u16* __restrict__ qkv,
                                                  float* __restrict__ cl,
                                                  float* __restrict__ S){
  __shared__ float Kl[64*36];
  __shared__ float Vl[64*36];
  const int t = threadIdx.x;
  const int bp = blockIdx.x, split = blockIdx.y;
  const int b = bp>>3, h = bp&7;
  const int ig = t&7, og = t>>3;
  float acc[4][4];
  float sacc[4] = {0.f,0.f,0.f,0.f};
  #pragma unroll
  for (int i=0;i<4;++i)
    #pragma unroll
    for (int j=0;j<4;++j) acc[i][j] = 0.f;
  for (int chunk = 0; chunk < 8; ++chunk){
    const int n = split*512 + chunk*64 + t;
    const u16* kp = qkv + (size_t)(b*HW + n)*768 + 256 + h*32;   // raw k
    const u16* vp = kp + 256;
    uint4 k4[4], v4[4];
    #pragma unroll
    for (int qq=0;qq<4;++qq){ k4[qq] = ((const uint4*)kp)[qq]; v4[qq] = ((const uint4*)vp)[qq]; }
    __syncthreads();
    #pragma unroll
    for (int qq=0;qq<4;++qq){
      float kv[8], vv[8]; unp8(k4[qq], kv); unp8(v4[qq], vv);
      #pragma unroll
      for (int e=0;e<8;++e) kv[e] = __expf(kv[e]);
      *(float4*)&Kl[t*36 + qq*8]     = float4{kv[0],kv[1],kv[2],kv[3]};
      *(float4*)&Kl[t*36 + qq*8 + 4] = float4{kv[4],kv[5],kv[6],kv[7]};
      *(float4*)&Vl[t*36 + qq*8]     = float4{vv[0],vv[1],vv[2],vv[3]};
      *(float4*)&Vl[t*36 + qq*8 + 4] = float4{vv[4],vv[5],vv[6],vv[7]};
    }
    __syncthreads();
    for (int p = 0; p < 64; ++p){
      float4 kf = *(const float4*)&Kl[p*36 + ig*4];
      float4 vf = *(const float4*)&Vl[p*36 + og*4];
      float kfa[4] = {kf.x,kf.y,kf.z,kf.w};
      float vfa[4] = {vf.x,vf.y,vf.z,vf.w};
      #pragma unroll
      for (int i=0;i<4;++i){
        sacc[i] += kfa[i];
        #pragma unroll
        for (int j=0;j<4;++j) acc[i][j] = fmaf(kfa[i], vfa[j], acc[i][j]);
      }
    }
  }
  #pragma unroll
  for (int i=0;i<4;++i)
    #pragma unroll
    for (int j=0;j<4;++j)
      atomicAdd(&cl[(size_t)bp*1024 + (ig*4+i)*32 + og*4+j], acc[i][j]);
  if (og == 0){
    #pragma unroll
    for (int i=0;i<4;++i) atomicAdd(&S[bp*32 + ig*4 + i], sacc[i]);
  }
}

// ---------------- fused content + depthwise-5x5 pos-lambda + combine ----------------
__global__ __launch_bounds__(256) void content_combine(const u16* __restrict__ qkv,
    const float* __restrict__ cl, const float* __restrict__ S,
    const float* __restrict__ rel, u16* __restrict__ res){
  __shared__ u16 vt[12800];
  __shared__ float cls[1024];
  __shared__ float relT[800];
  const int t = threadIdx.x;
  const int tile = blockIdx.x, h = blockIdx.y, b = blockIdx.z;
  const int x0 = (tile&3)*16, y0 = (tile>>2)*16;
  for (int idx = t; idx < 1024; idx += 256){
    const float sinv = 0.17677669529663687f / S[(b*8+h)*32 + (idx>>5)];
    cls[idx] = cl[(size_t)(b*8+h)*1024 + idx] * sinv;
  }
  for (int idx = t; idx < 800; idx += 256){
    int tap = idx>>5, ch = idx&31;
    relT[idx] = rel[ch*25 + tap];
  }
  #pragma unroll
  for (int i = 0; i < 7; ++i){
    int idx = t + 256*i;
    if (idx < 1600){
      int hp = idx>>2, g = idx&3;
      int hy = hp/20, hx = hp - hy*20;
      int y = y0 + hy - 2, x = x0 + hx - 2;
      uint4 v = uint4{0,0,0,0};
      if ((unsigned)y < 64u && (unsigned)x < 64u)
        v = *(const uint4*)&qkv[(size_t)(b*HW + y*64 + x)*768 + 512 + h*32 + g*8];
      *(uint4*)&vt[hp*32 + ((g ^ (hx&3))<<3)] = v;
    }
  }
  __syncthreads();
  const int py = t>>4, px = t&15;
  const int pix = b*HW + (y0+py)*64 + x0 + px;
  const u16* qp = qkv + (size_t)pix*768 + h*32;
  float qv[32];
  {
    uint4 q0 = ((const uint4*)qp)[0], q1 = ((const uint4*)qp)[1];
    uint4 q2 = ((const uint4*)qp)[2], q3 = ((const uint4*)qp)[3];
    unp8(q0, qv); unp8(q1, qv+8); unp8(q2, qv+16); unp8(q3, qv+24);
  }
  float outv[32];
  #pragma unroll
  for (int j=0;j<32;++j) outv[j] = 0.f;
  for (int i = 0; i < 32; ++i){
    const float qi = qv[i];
    #pragma unroll
    for (int g = 0; g < 8; ++g){
      float4 c4 = *(const float4*)&cls[i*32 + g*4];
      outv[g*4+0] = fmaf(qi, c4.x, outv[g*4+0]);
      outv[g*4+1] = fmaf(qi, c4.y, outv[g*4+1]);
      outv[g*4+2] = fmaf(qi, c4.z, outv[g*4+2]);
      outv[g*4+3] = fmaf(qi, c4.w, outv[g*4+3]);
    }
  }
  #pragma unroll
  for (int chg = 0; chg < 4; ++chg){
    float pos[8];
    #pragma unroll
    for (int j=0;j<8;++j) pos[j] = 0.f;
    #pragma unroll
    for (int dy = 0; dy < 5; ++dy)
      #pragma unroll
      for (int dx = 0; dx < 5; ++dx){
        int hx = px + dx;
        uint4 v4 = *(const uint4*)&vt[((py+dy)*20 + hx)*32 + ((chg ^ (hx&3))<<3)];
        float vv[8]; unp8(v4, vv);
        float4 r0 = *(const float4*)&relT[(dy*5+dx)*32 + chg*8];
        float4 r1 = *(const float4*)&relT[(dy*5+dx)*32 + chg*8 + 4];
        pos[0]=fmaf(r0.x, vv[0], pos[0]); pos[1]=fmaf(r0.y, vv[1], pos[1]);
        pos[2]=fmaf(r0.z, vv[2], pos[2]); pos[3]=fmaf(r0.w, vv[3], pos[3]);
        pos[4]=fmaf(r1.x, vv[4], pos[4]); pos[5]=fmaf(r1.y, vv[5], pos[5]);
        pos[6]=fmaf(r1.z, vv[6], pos[6]); pos[7]=fmaf(r1.w, vv[7], pos[7]);
      }
    #pragma unroll
    for (int j=0;j<8;++j) outv[chg*8+j] = fmaf(qv[chg*8+j], pos[j], outv[chg*8+j]);
  }
  u16* rp = res + (size_t)pix*256 + h*32;
  #pragma unroll
  for (int g = 0; g < 4; ++g){
    uint4 o_;
    o_.x = pack2(outv[g*8+0], outv[g*8+1]);
    o_.y = pack2(outv[g*8+2], outv[g*8+3]);
    o_.z = pack2(outv[g*8+4], outv[g*8+5]);
    o_.w = pack2(outv[g*8+6], outv[g*8+7]);
    ((uint4*)rp)[g] = o_;
  }
}

extern "C" void kernel_launch(void* const* d_in, const int* in_sizes, int n_in,
                              void* d_out, int out_size, void* d_ws, size_t ws_size,
                              hipStream_t stream) {
  const float* src   = (const float*)d_in[0];
  const float* rel   = (const float*)d_in[1];
  const float* qkv_w = (const float*)d_in[2];
  const float* cpe_w = (const float*)d_in[3];
  const float* cpe_b = (const float*)d_in[4];
  const float* out_w = (const float*)d_in[5];
  const float* out_b = (const float*)d_in[6];
  char* ws = (char*)d_ws;
  u16*   qkv  = (u16*)(ws);
  u16*   xpad = (u16*)(ws);                    // aliased (dead after conv)
  u16*   xbuf = (u16*)(ws + 100663296);
  float* cl   = (float*)(ws + 134217728);
  float* S    = (float*)(ws + 134742016);
  u16*   wrb  = (u16*)(ws + 134758400);
  u16*   wq   = (u16*)(ws + 135938048);
  u16*   wo   = (u16*)(ws + 136331264);

  zero_border<<<dim3(520), dim3(256), 0, stream>>>(xpad);
  to_nhwc<<<dim3(64, 16), dim3(256), 0, stream>>>(src, xpad);
  repack_w<<<dim3(3328), dim3(256), 0, stream>>>(cpe_w, qkv_w, out_w, wrb, wq, wo);
  conv_mfma<<<dim3(1024), dim3(256), 0, stream>>>(xpad, wrb, cpe_b, xbuf);
  gemm_mfma<768,6,false><<<dim3(3072), dim3(256), 0, stream>>>(xbuf, wq, nullptr, (void*)qkv);
  zero_cl<<<dim3(528), dim3(256), 0, stream>>>(cl);   // zeros cl + S (contiguous)
  lambda_kern<<<dim3(128, 8), dim3(64), 0, stream>>>(qkv, cl, S);
  content_combine<<<dim3(16, 8, 16), dim3(256), 0, stream>>>(qkv, cl, S, rel, xbuf);
  gemm_mfma<256,2,true><<<dim3(1024), dim3(256), 0, stream>>>(xbuf, wo, out_b, d_out);
}